// Round 15
// baseline (1793.485 us; speedup 1.0000x reference)
//
#include <hip/hip_runtime.h>
#include <hip/hip_bf16.h>

// ---------------- constants ----------------
#define NB   4
#define DIM  128
#define KC   64
#define HH   48
#define WW   900
#define WPAD 1100
#define WST  1160   // guarded stride for conv-phase buffers: col = w + 2, zeros outside [0,1100)
#define NT   30
#define OC1  256
#define OC2  512
#define OC3  1024

typedef __attribute__((ext_vector_type(8))) short bf16x8;
typedef __attribute__((ext_vector_type(4))) float f32x4;
typedef unsigned short u16;
typedef unsigned int u32;

__device__ __forceinline__ u16 f2bf(float f){
  __hip_bfloat16 h = __float2bfloat16(f);
  u16 u; __builtin_memcpy(&u, &h, 2); return u;
}
__device__ __forceinline__ float bf2f(u16 u){
  __hip_bfloat16 h; __builtin_memcpy(&h, &u, 2); return __bfloat162float(h);
}

typedef __attribute__((address_space(1))) const u32 g_u32;
typedef __attribute__((address_space(3))) u32 l_u32;
// async global->LDS, 16B per lane; LDS dest = uniform base + lane*16
__device__ __forceinline__ void gll16(const void* g, void* l){
  __builtin_amdgcn_global_load_lds((g_u32*)g, (l_u32*)l, 16, 0, 0);
}

// ---------------- VLAD branch (fp32) ----------------

__global__ __launch_bounds__(256) void vlad_softmax(const float* __restrict__ x,
    const float* __restrict__ conv_w, const float* __restrict__ conv_b, float* __restrict__ a){
  __shared__ float cwT[DIM*KC];
  __shared__ float cbs[KC];
  int t = threadIdx.x;
  for (int i = t; i < DIM*KC; i += 256){ int c = i >> 6, k = i & 63; cwT[i] = conv_w[k*DIM + c]; }
  if (t < KC) cbs[t] = conv_b[t];
  __syncthreads();
  int w = blockIdx.x*256 + t, h = blockIdx.y, n = blockIdx.z;
  bool ok = (w < WW);
  float lg[KC];
  #pragma unroll
  for (int k = 0; k < KC; ++k) lg[k] = cbs[k];
  const float* xp = x + (size_t)n*DIM*HH*WW + (size_t)h*WW + (ok ? w : 0);
  for (int c = 0; c < DIM; ++c){
    float xv = ok ? xp[(size_t)c*HH*WW] : 0.f;
    const float* cw = &cwT[c*KC];
    #pragma unroll
    for (int k = 0; k < KC; ++k) lg[k] += xv * cw[k];
  }
  float m = lg[0];
  #pragma unroll
  for (int k = 1; k < KC; ++k) m = fmaxf(m, lg[k]);
  float s = 0.f;
  #pragma unroll
  for (int k = 0; k < KC; ++k){ lg[k] = __expf(lg[k]-m); s += lg[k]; }
  float inv = 1.f/s;
  if (ok){
    float* dst = a + (((size_t)(n*HH + h))*WW + w)*KC;
    #pragma unroll
    for (int k = 0; k < KC; k += 4){
      float4 v = make_float4(lg[k]*inv, lg[k+1]*inv, lg[k+2]*inv, lg[k+3]*inv);
      *(float4*)&dst[k] = v;
    }
  }
}

// fused transpose+xa: reads x (NCHW) directly; per (n, segment of 10 padded-w).
__global__ __launch_bounds__(256) void vlad_xa3(const float* __restrict__ x, const float* __restrict__ a,
    const float* __restrict__ centers, float* __restrict__ ps){
  __shared__ float xw[2][10][132];
  __shared__ float aw[2][10][64];
  int t = threadIdx.x, s = blockIdx.x, n = blockIdx.y;
  int k = t >> 2, cb4 = t & 3;
  int p0 = s*10;
  int w0 = (p0 < 100) ? p0 + 800 : ((p0 < 1000) ? p0 - 100 : p0 - 1000);
  const float* xn = x + (size_t)n*DIM*HH*WW + w0;
  const float* an = a + (size_t)n*HH*WW*KC + (size_t)w0*KC;

  auto load = [&](int h, int buf){
    if (t < 128){
      const float* xr = xn + ((size_t)t*HH + h)*WW;
      #pragma unroll
      for (int w = 0; w < 10; ++w) xw[buf][w][t] = xr[w];
    } else {
      const float* ar = an + (size_t)h*WW*KC;
      int e0 = (t - 128)*5;
      #pragma unroll
      for (int q = 0; q < 5; ++q){ int e = e0 + q; aw[buf][e >> 6][e & 63] = ar[e]; }
    }
  };

  float acc[32];
  #pragma unroll
  for (int j = 0; j < 32; ++j) acc[j] = 0.f;
  float Sacc = 0.f;

  load(0, 0);
  for (int h = 0; h < HH; ++h){
    int buf = h & 1;
    __syncthreads();
    if (h + 1 < HH) load(h + 1, buf ^ 1);
    #pragma unroll 2
    for (int w = 0; w < 10; ++w){
      float av = aw[buf][w][k];
      Sacc += av;
      const float4* xr4 = (const float4*)&xw[buf][w][cb4*32];
      #pragma unroll
      for (int jj = 0; jj < 8; ++jj){
        float4 xv = xr4[jj];
        acc[jj*4+0] += av*xv.x; acc[jj*4+1] += av*xv.y;
        acc[jj*4+2] += av*xv.z; acc[jj*4+3] += av*xv.w;
      }
    }
    __syncthreads();
  }

  const float* ck = centers + (size_t)k*DIM + cb4*32;
  float* dst = ps + (((size_t)(n*KC + k))*110 + s)*DIM + cb4*32;
  #pragma unroll
  for (int jj = 0; jj < 8; ++jj){
    float4 o;
    o.x = acc[jj*4+0] - ck[jj*4+0]*Sacc;
    o.y = acc[jj*4+1] - ck[jj*4+1]*Sacc;
    o.z = acc[jj*4+2] - ck[jj*4+2]*Sacc;
    o.w = acc[jj*4+3] - ck[jj*4+3]*Sacc;
    *(float4*)&dst[jj*4] = o;
  }
}

// window tt = segments [3tt, 3tt+20); sum + intra (per-cluster) L2 norm
__global__ __launch_bounds__(128) void vlad_win2(const float* __restrict__ ps, float* __restrict__ vlad){
  int c = threadIdx.x, k = blockIdx.x, tt = blockIdx.y, n = blockIdx.z;
  const float* base = ps + ((size_t)(n*KC + k))*110*DIM + c;
  float v = 0.f;
  #pragma unroll
  for (int u = 0; u < 20; ++u) v += base[(3*tt + u)*DIM];
  float ss = v*v;
  #pragma unroll
  for (int m = 1; m < 64; m <<= 1) ss += __shfl_xor(ss, m);
  __shared__ float red[2];
  if ((c & 63) == 0) red[c >> 6] = ss;
  __syncthreads();
  float tot = red[0] + red[1];
  float inv = 1.f / fmaxf(sqrtf(tot), 1e-12f);
  vlad[(((size_t)(n*NT + tt))*KC + k)*DIM + c] = v*inv;
}

__global__ __launch_bounds__(256) void vlad_gnorm(float* __restrict__ vlad){
  int row = blockIdx.x, t = threadIdx.x;
  float4* v = (float4*)(vlad + (size_t)row*(KC*DIM));
  float4 r[8]; float ss = 0.f;
  #pragma unroll
  for (int i = 0; i < 8; ++i){
    r[i] = v[t + i*256];
    ss += r[i].x*r[i].x + r[i].y*r[i].y + r[i].z*r[i].z + r[i].w*r[i].w;
  }
  #pragma unroll
  for (int m = 1; m < 64; m <<= 1) ss += __shfl_xor(ss, m);
  __shared__ float red[4];
  if ((t & 63) == 0) red[t >> 6] = ss;
  __syncthreads();
  float tot = red[0]+red[1]+red[2]+red[3];
  float inv = 1.f / fmaxf(sqrtf(tot), 1e-12f);
  #pragma unroll
  for (int i = 0; i < 8; ++i){
    float4 o = r[i]; o.x*=inv; o.y*=inv; o.z*=inv; o.w*=inv;
    v[t + i*256] = o;
  }
}

// ---------------- conv tower (bf16 MFMA, NHWC, guarded stride WST) ----------------

__global__ __launch_bounds__(256) void build_xpb(const float* __restrict__ x, u16* __restrict__ xpb){
  __shared__ u16 tile[DIM][33];
  int t = threadIdx.x, h = blockIdx.y, n = blockIdx.z;
  int b0 = blockIdx.x*32;
  #pragma unroll
  for (int i = 0; i < 16; ++i){
    int e = t + i*256;
    int c = e >> 5, bl = e & 31;
    int b = b0 + bl, w = b - 2;
    float v = 0.f;
    if (w >= 0 && w < WPAD){
      int wsrc = (w + 800) % 900;
      v = x[((size_t)(n*DIM + c)*HH + h)*WW + wsrc];
    }
    tile[c][bl] = f2bf(v);
  }
  __syncthreads();
  #pragma unroll
  for (int i = 0; i < 16; ++i){
    int e = t + i*256;
    int bl = e >> 7, c = e & 127;
    int b = b0 + bl;
    if (b < WST) xpb[((size_t)(n*HH + h)*WST + b)*DIM + c] = tile[c][bl];
  }
}

// w OIHW fp32 -> wp fragment layout [tap][icb][k0i][lgp][oc][8ic] bf16
__global__ __launch_bounds__(256) void pack_w2(const float* __restrict__ w, u16* __restrict__ wp,
    int OC, int IC, int NICB){
  int idx = blockIdx.x*256 + threadIdx.x;
  int total = OC*IC*25;
  if (idx >= total) return;
  int e = idx & 7;
  int q = idx >> 3;
  int oc = q % OC;  int q2 = q / OC;
  int lgp = q2 & 3; int k0i = (q2 >> 2) & 3;
  int q3 = q2 >> 4;
  int icb = q3 % NICB; int tap = q3 / NICB;
  int ic = icb*128 + k0i*32 + lgp*8 + e;
  wp[idx] = f2bf(w[((size_t)oc*IC + ic)*25 + tap]);
}

// 5x5 conv pad 2. Round-15: block = 256oc x 64w (w-tile halved for grid-quantization:
// round-14 analysis showed all three convs' ~343us = ceil(blocks/512slots) x blockdur
// with ~290us of tail waste; finer tiles cut the quantization loss). 4 waves of
// 64oc x 64w, acc[4][4] (64 AGPR). A-ring depth 3 (Abuf[4]) since per-iter MFMA time
// halved (16 MFMA ~ 80cy; 3-deep = 240cy covers L2 ~250cy). sIn 68 rows, 2x17KB dbuf.
template<int IC, int OC, int H>
__global__ __launch_bounds__(256,2) void conv5x5(const u16* __restrict__ in, const u16* __restrict__ wp,
    const float* __restrict__ bias, u16* __restrict__ out){
  constexpr int NICB = IC/128;
  constexpr int LN = (NICB==1?0:(NICB==2?1:2));
  __shared__ u16 sIn[2][68*128];   // [buf][row][ic], 256B/row, chunk-swizzled
  int t = threadIdx.x;
  int wave = t >> 6, lane = t & 63, lr = lane & 15, lgp = lane >> 4;
  int w0  = blockIdx.x * 64;
  int ocb = blockIdx.y * 256;
  int nh = blockIdx.z; int n = nh / H, h = nh % H;
  int wo_oc = wave*64;
  f32x4 acc[4][4] = {};
  const u16* inN = in + (size_t)n*H*WST*IC;   // col0 = w=-2
  const size_t laneA = (size_t)(ocb + wo_oc + lr)*8;  // per-lane A offset within a panel
  int dhlo = (2-h > 0) ? (2-h) : 0;
  int dhhi = (H+1-h < 4) ? (H+1-h) : 4;
  int nslab = (dhhi - dhlo + 1) << LN;

  auto stage = [&](int slab_, int buf_){
    int dh = dhlo + (slab_ >> LN);
    int icb = slab_ & (NICB-1);
    const u16* rowbase = inN + (size_t)(h + dh - 2)*WST*IC + (size_t)icb*128;
    for (int i = wave; i < 17; i += 4){   // 68 rows x 16 chunks = 1088 = 17 instrs
      int qq = i*64 + lane;
      int r = qq >> 4, cp = qq & 15;
      int c = cp ^ (r & 7);
      gll16(rowbase + (size_t)(w0 + r)*IC + c*8, &sIn[buf_][i*512]);
    }
  };

  stage(0, 0);
  __syncthreads();   // drain prologue staging

  for (int slab = 0; slab < nslab; ++slab){
    int buf = slab & 1;
    if (slab + 1 < nslab) stage(slab + 1, buf ^ 1);   // lands during this slab's MFMAs
    int dh = dhlo + (slab >> LN);
    int icb = slab & (NICB-1);
    // slab weight base: [5 dw][4 k0i][4 lgp][OC][8]
    const u16* wslab = wp + (size_t)(dh*5*NICB + icb)*16*OC*8 + laneA;
    const u16* sB = &sIn[buf][0];
    bf16x8 Abuf[4][4];
    #pragma unroll
    for (int pi = 0; pi < 3; ++pi){   // preload i=0,1,2
      const u16* ap = wslab + (size_t)((pi >> 2)*NICB*16 + ((pi & 3)*4 + lgp))*OC*8;
      #pragma unroll
      for (int ja = 0; ja < 4; ++ja) Abuf[pi][ja] = *(const bf16x8*)(ap + (size_t)ja*16*8);
    }
    #pragma unroll
    for (int dw = 0; dw < 5; ++dw){
      #pragma unroll
      for (int k0i = 0; k0i < 4; ++k0i){
        constexpr int NI = 20;
        const int i = dw*4 + k0i;
        {  // prefetch i+3 into slot (i+3)%4
          const int pn = (i + 3 < NI) ? (i + 3) : (NI - 1);
          const u16* ap = wslab + (size_t)((pn >> 2)*NICB*16 + ((pn & 3)*4 + lgp))*OC*8;
          #pragma unroll
          for (int ja = 0; ja < 4; ++ja) Abuf[(i + 3) % 4][ja] = *(const bf16x8*)(ap + (size_t)ja*16*8);
        }
        bf16x8 B[4];
        #pragma unroll
        for (int jb = 0; jb < 4; ++jb){
          int br = jb*16 + lr + dw;
          B[jb] = *(const bf16x8*)&sB[br*128 + (((k0i*4 + lgp) ^ (br & 7)) << 3)];
        }
        __builtin_amdgcn_s_setprio(1);
        #pragma unroll
        for (int ja = 0; ja < 4; ++ja)
          #pragma unroll
          for (int jb = 0; jb < 4; ++jb)
            acc[ja][jb] = __builtin_amdgcn_mfma_f32_16x16x32_bf16(Abuf[i % 4][ja], B[jb], acc[ja][jb], 0, 0, 0);
        __builtin_amdgcn_s_setprio(0);
      }
    }
    __syncthreads();   // slab boundary: drains (old) prefetch, protects buf^1 for reuse
  }

  u16* outP = out + ((size_t)(n*H + h)*WST + 2)*OC;  // col = w+2
  #pragma unroll
  for (int ja = 0; ja < 4; ++ja){
    int oc = ocb + wo_oc + ja*16 + lgp*4;
    float4 bv = *(const float4*)&bias[oc];
    #pragma unroll
    for (int jb = 0; jb < 4; ++jb){
      int wg = w0 + jb*16 + lr;
      if (wg < WPAD){
        f32x4 av = acc[ja][jb];
        ushort4 o;
        o.x = f2bf(av[0] + bv.x);
        o.y = f2bf(av[1] + bv.y);
        o.z = f2bf(av[2] + bv.z);
        o.w = f2bf(av[3] + bv.w);
        *(ushort4*)(outP + (size_t)wg*OC + oc) = o;
      }
    }
  }
}

// leaky(0.2) + maxpool 3x3 stride(3,1); 4 oc/thread
__global__ __launch_bounds__(256) void pool1k(const u16* __restrict__ in, u16* __restrict__ out){
  int t = threadIdx.x;
  int wb = blockIdx.x*4 + (t >> 6);
  int oc = (t & 63)*4;
  int ho = blockIdx.y, n = blockIdx.z;
  int wo = wb - 2;
  float m0=0.f,m1=0.f,m2=0.f,m3=0.f;
  if (wo >= 0 && wo < WPAD){
    m0=m1=m2=m3=-1e30f;
    #pragma unroll
    for (int kh = 0; kh < 3; ++kh){
      const u16* row = in + ((size_t)(n*HH + ho*3 + kh)*WST + 2)*OC1 + oc;
      #pragma unroll
      for (int kw = 0; kw < 3; ++kw){
        int wi = wo - 1 + kw;
        if (wi >= 0 && wi < WPAD){
          ushort4 v = *(const ushort4*)(row + (size_t)wi*OC1);
          m0 = fmaxf(m0, bf2f(v.x)); m1 = fmaxf(m1, bf2f(v.y));
          m2 = fmaxf(m2, bf2f(v.z)); m3 = fmaxf(m3, bf2f(v.w));
        }
      }
    }
    m0 = (m0>0.f)?m0:0.2f*m0; m1 = (m1>0.f)?m1:0.2f*m1;
    m2 = (m2>0.f)?m2:0.2f*m2; m3 = (m3>0.f)?m3:0.2f*m3;
  }
  ushort4 o; o.x=f2bf(m0); o.y=f2bf(m1); o.z=f2bf(m2); o.w=f2bf(m3);
  *(ushort4*)(out + ((size_t)(n*16 + ho)*WST + wb)*OC1 + oc) = o;
}

// leaky(0.2) + maxpool 4x5 stride(4,1); 4 oc/thread
__global__ __launch_bounds__(256) void pool2k(const u16* __restrict__ in, u16* __restrict__ out){
  int t = threadIdx.x;
  int wb = blockIdx.x*2 + (t >> 7);
  int oc = (t & 127)*4;
  int ho = blockIdx.y, n = blockIdx.z;
  int wo = wb - 2;
  float m0=0.f,m1=0.f,m2=0.f,m3=0.f;
  if (wo >= 0 && wo < WPAD){
    m0=m1=m2=m3=-1e30f;
    #pragma unroll
    for (int kh = 0; kh < 4; ++kh){
      const u16* row = in + ((size_t)(n*16 + ho*4 + kh)*WST + 2)*OC2 + oc;
      #pragma unroll
      for (int kw = 0; kw < 5; ++kw){
        int wi = wo - 2 + kw;
        if (wi >= 0 && wi < WPAD){
          ushort4 v = *(const ushort4*)(row + (size_t)wi*OC2);
          m0 = fmaxf(m0, bf2f(v.x)); m1 = fmaxf(m1, bf2f(v.y));
          m2 = fmaxf(m2, bf2f(v.z)); m3 = fmaxf(m3, bf2f(v.w));
        }
      }
    }
    m0 = (m0>0.f)?m0:0.2f*m0; m1 = (m1>0.f)?m1:0.2f*m1;
    m2 = (m2>0.f)?m2:0.2f*m2; m3 = (m3>0.f)?m3:0.2f*m3;
  }
  ushort4 o; o.x=f2bf(m0); o.y=f2bf(m1); o.z=f2bf(m2); o.w=f2bf(m3);
  *(ushort4*)(out + ((size_t)(n*4 + ho)*WST + wb)*OC2 + oc) = o;
}

// hierarchical pool3 stage A: per-10w-segment max over 4 h rows -> segmax [n][110][1024] fp32
__global__ __launch_bounds__(256) void pool3a(const u16* __restrict__ in, float* __restrict__ segmax){
  int seg = blockIdx.x, n = blockIdx.y;
  int oc = threadIdx.x*4;
  float m0=-1e30f,m1=-1e30f,m2=-1e30f,m3=-1e30f;
  #pragma unroll
  for (int hh = 0; hh < 4; ++hh){
    const u16* row = in + ((size_t)(n*4 + hh)*WST + 2 + seg*10)*OC3 + oc;
    #pragma unroll
    for (int p = 0; p < 10; ++p){
      ushort4 v = *(const ushort4*)(row + (size_t)p*OC3);
      m0 = fmaxf(m0, bf2f(v.x)); m1 = fmaxf(m1, bf2f(v.y));
      m2 = fmaxf(m2, bf2f(v.z)); m3 = fmaxf(m3, bf2f(v.w));
    }
  }
  float* dst = segmax + ((size_t)n*110 + seg)*1024 + oc;
  dst[0]=m0; dst[1]=m1; dst[2]=m2; dst[3]=m3;
}

// combine 20 segment maxes per window, L2 normalize -> xf [row][1024]
__global__ __launch_bounds__(256) void xf_norm(const float* __restrict__ segmax, float* __restrict__ xf){
  int row = blockIdx.x, t = threadIdx.x;
  int n = row / NT, tt = row % NT;
  const float* base = segmax + (size_t)n*110*1024;
  float v[4]; float ss = 0.f;
  #pragma unroll
  for (int j = 0; j < 4; ++j){
    int oc = t + j*256;
    float m = -1e30f;
    #pragma unroll
    for (int u = 0; u < 20; ++u) m = fmaxf(m, base[(size_t)(3*tt + u)*1024 + oc]);
    v[j] = m; ss += m*m;
  }
  #pragma unroll
  for (int m = 1; m < 64; m <<= 1) ss += __shfl_xor(ss, m);
  __shared__ float red[4];
  if ((t & 63) == 0) red[t >> 6] = ss;
  __syncthreads();
  float tot = red[0]+red[1]+red[2]+red[3];
  float inv = 1.f/fmaxf(sqrtf(tot), 1e-12f);
  float* dst = xf + (size_t)row*OC3;
  #pragma unroll
  for (int j = 0; j < 4; ++j) dst[t + j*256] = v[j]*inv;
}

// ---- final head: split-K GEMM ----
__global__ __launch_bounds__(256) void mlp_part(const float* __restrict__ vlad, const float* __restrict__ xf,
    const float* __restrict__ W, float* __restrict__ part){
  __shared__ float feat[4][256];
  int kc = blockIdx.x, rb = blockIdx.y, t = threadIdx.x;
  int i0 = kc*256;
  #pragma unroll
  for (int r = 0; r < 4; ++r){
    int row = rb*4 + r;
    int i = i0 + t;
    feat[r][t] = (i < 8192) ? vlad[(size_t)row*8192 + i] : xf[(size_t)row*1024 + (i - 8192)];
  }
  __syncthreads();
  const float* wr = W + (size_t)t*9216 + i0;
  float a0=0.f, a1=0.f, a2=0.f, a3=0.f;
  for (int i = 0; i < 256; i += 4){
    float4 wv = *(const float4*)&wr[i];
    a0 += feat[0][i]*wv.x + feat[0][i+1]*wv.y + feat[0][i+2]*wv.z + feat[0][i+3]*wv.w;
    a1 += feat[1][i]*wv.x + feat[1][i+1]*wv.y + feat[1][i+2]*wv.z + feat[1][i+3]*wv.w;
    a2 += feat[2][i]*wv.x + feat[2][i+1]*wv.y + feat[2][i+2]*wv.z + feat[2][i+3]*wv.w;
    a3 += feat[3][i]*wv.x + feat[3][i+1]*wv.y + feat[3][i+2]*wv.z + feat[3][i+3]*wv.w;
  }
  float* p0 = part + (((size_t)(rb*4 + 0)*36 + kc))*256 + t;
  p0[0]          = a0;
  p0[36*256]     = a1;
  p0[2*36*256]   = a2;
  p0[3*36*256]   = a3;
}

__global__ __launch_bounds__(256) void mlp_reduce(const float* __restrict__ part, const float* __restrict__ b,
    float* __restrict__ out){
  int row = blockIdx.x, t = threadIdx.x;
  const float* pr = part + (size_t)row*36*256 + t;
  float acc = b[t];
  #pragma unroll
  for (int kc = 0; kc < 36; ++kc) acc += pr[kc*256];
  float ss = acc*acc;
  #pragma unroll
  for (int m = 1; m < 64; m <<= 1) ss += __shfl_xor(ss, m);
  __shared__ float red[4];
  if ((t & 63) == 0) red[t >> 6] = ss;
  __syncthreads();
  float tot = red[0]+red[1]+red[2]+red[3];
  float inv = 1.f/fmaxf(sqrtf(tot), 1e-12f);
  out[(size_t)row*256 + t] = acc*inv;
}

// ---------------- launch ----------------
extern "C" void kernel_launch(void* const* d_in, const int* in_sizes, int n_in,
                              void* d_out, int out_size, void* d_ws, size_t ws_size,
                              hipStream_t stream){
  const float* x       = (const float*)d_in[0];
  const float* centers = (const float*)d_in[1];
  const float* conv_w  = (const float*)d_in[2];
  const float* conv_b  = (const float*)d_in[3];
  const float* w1      = (const float*)d_in[4];
  const float* b1      = (const float*)d_in[5];
  const float* w2      = (const float*)d_in[6];
  const float* b2      = (const float*)d_in[7];
  const float* w3      = (const float*)d_in[8];
  const float* b3      = (const float*)d_in[9];
  const float* mlp_w   = (const float*)d_in[10];
  const float* mlp_b   = (const float*)d_in[11];
  float* out = (float*)d_out;
  char* ws = (char*)d_ws;
  const size_t MB = 1ull << 20;
  if (ws_size < 248*MB) return;

  // persistent small buffers
  float* vlad  = (float*)(ws + 0);        // 3.75 MiB
  float* xf    = (float*)(ws + 4*MB);     // 0.47 MiB
  float* xfraw = (float*)(ws + 5*MB);     // 1.76 MiB (segmax [4][110][1024] fp32)
  char*  AR    = ws + 7*MB;               // arena (241 MiB), phase-reused
  // VLAD phase
  float* a  = (float*)(AR + 85*MB);       // 42.2 MiB (dead after vlad_xa3)
  float* ps = (float*)(AR + 128*MB);      // 14.4 MiB (dead after vlad_win2)
  // conv phase
  u16* xpb = (u16*)(AR + 0);              // 54.4 MiB
  u16* wp1 = (u16*)(AR + 55*MB);          // 1.6 MiB
  u16* wp2 = (u16*)(AR + 57*MB);          // 6.25 MiB
  u16* wp3 = (u16*)(AR + 64*MB);          // 25 MiB
  u16* h1  = (u16*)(AR + 89*MB);          // 108.75 MiB (over a/ps)
  u16* p1  = (u16*)(AR + 0);              // 36.25 MiB (over xpb)
  u16* h2  = (u16*)(AR + 89*MB);          // 72.5 MiB (over h1)
  u16* p2  = (u16*)(AR + 163*MB);         // 18.1 MiB
  u16* h3  = (u16*)(AR + 0);              // 36.25 MiB (over p1)
  float* part = (float*)(AR + 200*MB);    // 4.4 MiB

  // ---- VLAD (fp32) ----
  vlad_softmax<<<dim3(4,HH,NB), 256, 0, stream>>>(x, conv_w, conv_b, a);
  vlad_xa3<<<dim3(110,NB), 256, 0, stream>>>(x, a, centers, ps);
  vlad_win2<<<dim3(KC,NT,NB), 128, 0, stream>>>(ps, vlad);
  vlad_gnorm<<<dim3(NB*NT), 256, 0, stream>>>(vlad);

  // ---- conv tower (64-wide w tiles for finer grid quantization) ----
  pack_w2<<<dim3(3200),  256, 0, stream>>>(w1, wp1, OC1, DIM, 1);
  pack_w2<<<dim3(12800), 256, 0, stream>>>(w2, wp2, OC2, OC1, 2);
  pack_w2<<<dim3(51200), 256, 0, stream>>>(w3, wp3, OC3, OC2, 4);
  build_xpb<<<dim3(37,HH,NB), 256, 0, stream>>>(x, xpb);
  conv5x5<128,256,48><<<dim3(18, OC1/256, NB*HH), 256, 0, stream>>>(xpb, wp1, b1, h1);  // 3456
  pool1k<<<dim3(WST/4,16,NB), 256, 0, stream>>>(h1, p1);
  conv5x5<256,512,16><<<dim3(18, OC2/256, NB*16), 256, 0, stream>>>(p1, wp2, b2, h2);   // 2304
  pool2k<<<dim3(WST/2,4,NB), 256, 0, stream>>>(h2, p2);
  conv5x5<512,1024,4><<<dim3(18, OC3/256, NB*4), 256, 0, stream>>>(p2, wp3, b3, h3);    // 1152
  pool3a<<<dim3(110,NB), 256, 0, stream>>>(h3, xfraw);
  xf_norm<<<dim3(NB*NT), 256, 0, stream>>>(xfraw, xf);

  // ---- head (split-K) ----
  mlp_part<<<dim3(36,30), 256, 0, stream>>>(vlad, xf, mlp_w, part);
  mlp_reduce<<<dim3(NB*NT), 256, 0, stream>>>(part, mlp_b, out);
}

// Round 16
// 1733.935 us; speedup vs baseline: 1.0343x; 1.0343x over previous
//
#include <hip/hip_runtime.h>
#include <hip/hip_bf16.h>

// ---------------- constants ----------------
#define NB   4
#define DIM  128
#define KC   64
#define HH   48
#define WW   900
#define WPAD 1100
#define WST  1160   // guarded stride for conv-phase buffers: col = w + 2, zeros outside [0,1100)
#define NT   30
#define OC1  256
#define OC2  512
#define OC3  1024

typedef __attribute__((ext_vector_type(8))) short bf16x8;
typedef __attribute__((ext_vector_type(4))) float f32x4;
typedef unsigned short u16;
typedef unsigned int u32;

__device__ __forceinline__ u16 f2bf(float f){
  __hip_bfloat16 h = __float2bfloat16(f);
  u16 u; __builtin_memcpy(&u, &h, 2); return u;
}
__device__ __forceinline__ float bf2f(u16 u){
  __hip_bfloat16 h; __builtin_memcpy(&h, &u, 2); return __bfloat162float(h);
}

typedef __attribute__((address_space(1))) const u32 g_u32;
typedef __attribute__((address_space(3))) u32 l_u32;
// async global->LDS, 16B per lane; LDS dest = uniform base + lane*16
__device__ __forceinline__ void gll16(const void* g, void* l){
  __builtin_amdgcn_global_load_lds((g_u32*)g, (l_u32*)l, 16, 0, 0);
}

// ---------------- VLAD branch (fp32) ----------------

__global__ __launch_bounds__(256) void vlad_softmax(const float* __restrict__ x,
    const float* __restrict__ conv_w, const float* __restrict__ conv_b, float* __restrict__ a){
  __shared__ float cwT[DIM*KC];
  __shared__ float cbs[KC];
  int t = threadIdx.x;
  for (int i = t; i < DIM*KC; i += 256){ int c = i >> 6, k = i & 63; cwT[i] = conv_w[k*DIM + c]; }
  if (t < KC) cbs[t] = conv_b[t];
  __syncthreads();
  int w = blockIdx.x*256 + t, h = blockIdx.y, n = blockIdx.z;
  bool ok = (w < WW);
  float lg[KC];
  #pragma unroll
  for (int k = 0; k < KC; ++k) lg[k] = cbs[k];
  const float* xp = x + (size_t)n*DIM*HH*WW + (size_t)h*WW + (ok ? w : 0);
  for (int c = 0; c < DIM; ++c){
    float xv = ok ? xp[(size_t)c*HH*WW] : 0.f;
    const float* cw = &cwT[c*KC];
    #pragma unroll
    for (int k = 0; k < KC; ++k) lg[k] += xv * cw[k];
  }
  float m = lg[0];
  #pragma unroll
  for (int k = 1; k < KC; ++k) m = fmaxf(m, lg[k]);
  float s = 0.f;
  #pragma unroll
  for (int k = 0; k < KC; ++k){ lg[k] = __expf(lg[k]-m); s += lg[k]; }
  float inv = 1.f/s;
  if (ok){
    float* dst = a + (((size_t)(n*HH + h))*WW + w)*KC;
    #pragma unroll
    for (int k = 0; k < KC; k += 4){
      float4 v = make_float4(lg[k]*inv, lg[k+1]*inv, lg[k+2]*inv, lg[k+3]*inv);
      *(float4*)&dst[k] = v;
    }
  }
}

// fused transpose+xa: reads x (NCHW) directly; per (n, segment of 10 padded-w).
__global__ __launch_bounds__(256) void vlad_xa3(const float* __restrict__ x, const float* __restrict__ a,
    const float* __restrict__ centers, float* __restrict__ ps){
  __shared__ float xw[2][10][132];
  __shared__ float aw[2][10][64];
  int t = threadIdx.x, s = blockIdx.x, n = blockIdx.y;
  int k = t >> 2, cb4 = t & 3;
  int p0 = s*10;
  int w0 = (p0 < 100) ? p0 + 800 : ((p0 < 1000) ? p0 - 100 : p0 - 1000);
  const float* xn = x + (size_t)n*DIM*HH*WW + w0;
  const float* an = a + (size_t)n*HH*WW*KC + (size_t)w0*KC;

  auto load = [&](int h, int buf){
    if (t < 128){
      const float* xr = xn + ((size_t)t*HH + h)*WW;
      #pragma unroll
      for (int w = 0; w < 10; ++w) xw[buf][w][t] = xr[w];
    } else {
      const float* ar = an + (size_t)h*WW*KC;
      int e0 = (t - 128)*5;
      #pragma unroll
      for (int q = 0; q < 5; ++q){ int e = e0 + q; aw[buf][e >> 6][e & 63] = ar[e]; }
    }
  };

  float acc[32];
  #pragma unroll
  for (int j = 0; j < 32; ++j) acc[j] = 0.f;
  float Sacc = 0.f;

  load(0, 0);
  for (int h = 0; h < HH; ++h){
    int buf = h & 1;
    __syncthreads();
    if (h + 1 < HH) load(h + 1, buf ^ 1);
    #pragma unroll 2
    for (int w = 0; w < 10; ++w){
      float av = aw[buf][w][k];
      Sacc += av;
      const float4* xr4 = (const float4*)&xw[buf][w][cb4*32];
      #pragma unroll
      for (int jj = 0; jj < 8; ++jj){
        float4 xv = xr4[jj];
        acc[jj*4+0] += av*xv.x; acc[jj*4+1] += av*xv.y;
        acc[jj*4+2] += av*xv.z; acc[jj*4+3] += av*xv.w;
      }
    }
    __syncthreads();
  }

  const float* ck = centers + (size_t)k*DIM + cb4*32;
  float* dst = ps + (((size_t)(n*KC + k))*110 + s)*DIM + cb4*32;
  #pragma unroll
  for (int jj = 0; jj < 8; ++jj){
    float4 o;
    o.x = acc[jj*4+0] - ck[jj*4+0]*Sacc;
    o.y = acc[jj*4+1] - ck[jj*4+1]*Sacc;
    o.z = acc[jj*4+2] - ck[jj*4+2]*Sacc;
    o.w = acc[jj*4+3] - ck[jj*4+3]*Sacc;
    *(float4*)&dst[jj*4] = o;
  }
}

// window tt = segments [3tt, 3tt+20); sum + intra (per-cluster) L2 norm
__global__ __launch_bounds__(128) void vlad_win2(const float* __restrict__ ps, float* __restrict__ vlad){
  int c = threadIdx.x, k = blockIdx.x, tt = blockIdx.y, n = blockIdx.z;
  const float* base = ps + ((size_t)(n*KC + k))*110*DIM + c;
  float v = 0.f;
  #pragma unroll
  for (int u = 0; u < 20; ++u) v += base[(3*tt + u)*DIM];
  float ss = v*v;
  #pragma unroll
  for (int m = 1; m < 64; m <<= 1) ss += __shfl_xor(ss, m);
  __shared__ float red[2];
  if ((c & 63) == 0) red[c >> 6] = ss;
  __syncthreads();
  float tot = red[0] + red[1];
  float inv = 1.f / fmaxf(sqrtf(tot), 1e-12f);
  vlad[(((size_t)(n*NT + tt))*KC + k)*DIM + c] = v*inv;
}

__global__ __launch_bounds__(256) void vlad_gnorm(float* __restrict__ vlad){
  int row = blockIdx.x, t = threadIdx.x;
  float4* v = (float4*)(vlad + (size_t)row*(KC*DIM));
  float4 r[8]; float ss = 0.f;
  #pragma unroll
  for (int i = 0; i < 8; ++i){
    r[i] = v[t + i*256];
    ss += r[i].x*r[i].x + r[i].y*r[i].y + r[i].z*r[i].z + r[i].w*r[i].w;
  }
  #pragma unroll
  for (int m = 1; m < 64; m <<= 1) ss += __shfl_xor(ss, m);
  __shared__ float red[4];
  if ((t & 63) == 0) red[t >> 6] = ss;
  __syncthreads();
  float tot = red[0]+red[1]+red[2]+red[3];
  float inv = 1.f / fmaxf(sqrtf(tot), 1e-12f);
  #pragma unroll
  for (int i = 0; i < 8; ++i){
    float4 o = r[i]; o.x*=inv; o.y*=inv; o.z*=inv; o.w*=inv;
    v[t + i*256] = o;
  }
}

// ---------------- conv tower (bf16 MFMA, NHWC, guarded stride WST) ----------------

__global__ __launch_bounds__(256) void build_xpb(const float* __restrict__ x, u16* __restrict__ xpb){
  __shared__ u16 tile[DIM][33];
  int t = threadIdx.x, h = blockIdx.y, n = blockIdx.z;
  int b0 = blockIdx.x*32;
  #pragma unroll
  for (int i = 0; i < 16; ++i){
    int e = t + i*256;
    int c = e >> 5, bl = e & 31;
    int b = b0 + bl, w = b - 2;
    float v = 0.f;
    if (w >= 0 && w < WPAD){
      int wsrc = (w + 800) % 900;
      v = x[((size_t)(n*DIM + c)*HH + h)*WW + wsrc];
    }
    tile[c][bl] = f2bf(v);
  }
  __syncthreads();
  #pragma unroll
  for (int i = 0; i < 16; ++i){
    int e = t + i*256;
    int bl = e >> 7, c = e & 127;
    int b = b0 + bl;
    if (b < WST) xpb[((size_t)(n*HH + h)*WST + b)*DIM + c] = tile[c][bl];
  }
}

// w OIHW fp32 -> wp fragment layout [tap][icb][k0i][lgp][oc][8ic] bf16
__global__ __launch_bounds__(256) void pack_w2(const float* __restrict__ w, u16* __restrict__ wp,
    int OC, int IC, int NICB){
  int idx = blockIdx.x*256 + threadIdx.x;
  int total = OC*IC*25;
  if (idx >= total) return;
  int e = idx & 7;
  int q = idx >> 3;
  int oc = q % OC;  int q2 = q / OC;
  int lgp = q2 & 3; int k0i = (q2 >> 2) & 3;
  int q3 = q2 >> 4;
  int icb = q3 % NICB; int tap = q3 / NICB;
  int ic = icb*128 + k0i*32 + lgp*8 + e;
  wp[idx] = f2bf(w[((size_t)oc*IC + ic)*25 + tap]);
}

// 5x5 conv pad 2. Round-16: block = 128oc x 128w (OC halved vs round-14 for finer
// grid quantization -- total A-traffic INVARIANT: 2x blocks x 1/2 slab bytes, unlike
// round-15's w-split which doubled it). 4 waves of 64oc x 64w, acc[4][4]. sIn
// unchanged (2x33KB dbuf, one-slab-ahead gll16, one barrier/slab). A-ring depth 4
// (Abuf[5]): 16-MFMA iters ~78cy, 4-deep = 312cy covers L2 ~250-300cy.
template<int IC, int OC, int H>
__global__ __launch_bounds__(256,2) void conv5x5(const u16* __restrict__ in, const u16* __restrict__ wp,
    const float* __restrict__ bias, u16* __restrict__ out){
  constexpr int NICB = IC/128;
  constexpr int LN = (NICB==1?0:(NICB==2?1:2));
  __shared__ u16 sIn[2][132*128];   // [buf][row][ic], 256B/row, chunk-swizzled
  int t = threadIdx.x;
  int wave = t >> 6, lane = t & 63, lr = lane & 15, lgp = lane >> 4;
  int w0  = blockIdx.x * 128;
  int ocb = blockIdx.y * 128;
  int nh = blockIdx.z; int n = nh / H, h = nh % H;
  int wo_oc = (wave & 1)*64, wo_w = (wave >> 1)*64;
  f32x4 acc[4][4] = {};
  const u16* inN = in + (size_t)n*H*WST*IC;   // col0 = w=-2
  const size_t laneA = (size_t)(ocb + wo_oc + lr)*8;  // per-lane A offset within a panel
  int dhlo = (2-h > 0) ? (2-h) : 0;
  int dhhi = (H+1-h < 4) ? (H+1-h) : 4;
  int nslab = (dhhi - dhlo + 1) << LN;

  auto stage = [&](int slab_, int buf_){
    int dh = dhlo + (slab_ >> LN);
    int icb = slab_ & (NICB-1);
    const u16* rowbase = inN + (size_t)(h + dh - 2)*WST*IC + (size_t)icb*128;
    for (int i = wave; i < 33; i += 4){
      int qq = i*64 + lane;
      int r = qq >> 4, cp = qq & 15;
      int c = cp ^ (r & 7);
      gll16(rowbase + (size_t)(w0 + r)*IC + c*8, &sIn[buf_][i*512]);
    }
  };
  auto wbase = [&](int slab_) -> const u16* {
    int dh = dhlo + (slab_ >> LN);
    int icb = slab_ & (NICB-1);
    return wp + (size_t)(dh*5*NICB + icb)*16*OC*8 + laneA;
  };

  stage(0, 0);
  __syncthreads();   // drain prologue staging

  for (int slab = 0; slab < nslab; ++slab){
    int buf = slab & 1;
    if (slab + 1 < nslab) stage(slab + 1, buf ^ 1);   // lands during this slab's MFMAs
    const u16* wslab = wbase(slab);
    const u16* sB = &sIn[buf][0];
    bf16x8 Abuf[5][4];
    #pragma unroll
    for (int pi = 0; pi < 4; ++pi){   // preload i=0..3
      const u16* ap = wslab + (size_t)((pi >> 2)*NICB*16 + ((pi & 3)*4 + lgp))*OC*8;
      #pragma unroll
      for (int ja = 0; ja < 4; ++ja) Abuf[pi][ja] = *(const bf16x8*)(ap + (size_t)ja*16*8);
    }
    #pragma unroll
    for (int dw = 0; dw < 5; ++dw){
      #pragma unroll
      for (int k0i = 0; k0i < 4; ++k0i){
        constexpr int NI = 20;
        const int i = dw*4 + k0i;
        {  // prefetch i+4 into slot (i+4)%5
          const int pn = (i + 4 < NI) ? (i + 4) : (NI - 1);
          const u16* ap = wslab + (size_t)((pn >> 2)*NICB*16 + ((pn & 3)*4 + lgp))*OC*8;
          #pragma unroll
          for (int ja = 0; ja < 4; ++ja) Abuf[(i + 4) % 5][ja] = *(const bf16x8*)(ap + (size_t)ja*16*8);
        }
        bf16x8 B[4];
        #pragma unroll
        for (int jb = 0; jb < 4; ++jb){
          int br = wo_w + jb*16 + lr + dw;
          B[jb] = *(const bf16x8*)&sB[br*128 + (((k0i*4 + lgp) ^ (br & 7)) << 3)];
        }
        __builtin_amdgcn_s_setprio(1);
        #pragma unroll
        for (int ja = 0; ja < 4; ++ja)
          #pragma unroll
          for (int jb = 0; jb < 4; ++jb)
            acc[ja][jb] = __builtin_amdgcn_mfma_f32_16x16x32_bf16(Abuf[i % 5][ja], B[jb], acc[ja][jb], 0, 0, 0);
        __builtin_amdgcn_s_setprio(0);
      }
    }
    __syncthreads();   // slab boundary: drains (old) prefetch, protects buf^1 for reuse
  }

  u16* outP = out + ((size_t)(n*H + h)*WST + 2)*OC;  // col = w+2
  #pragma unroll
  for (int ja = 0; ja < 4; ++ja){
    int oc = ocb + wo_oc + ja*16 + lgp*4;
    float4 bv = *(const float4*)&bias[oc];
    #pragma unroll
    for (int jb = 0; jb < 4; ++jb){
      int wg = w0 + wo_w + jb*16 + lr;
      if (wg < WPAD){
        f32x4 av = acc[ja][jb];
        ushort4 o;
        o.x = f2bf(av[0] + bv.x);
        o.y = f2bf(av[1] + bv.y);
        o.z = f2bf(av[2] + bv.z);
        o.w = f2bf(av[3] + bv.w);
        *(ushort4*)(outP + (size_t)wg*OC + oc) = o;
      }
    }
  }
}

// leaky(0.2) + maxpool 3x3 stride(3,1); 4 oc/thread
__global__ __launch_bounds__(256) void pool1k(const u16* __restrict__ in, u16* __restrict__ out){
  int t = threadIdx.x;
  int wb = blockIdx.x*4 + (t >> 6);
  int oc = (t & 63)*4;
  int ho = blockIdx.y, n = blockIdx.z;
  int wo = wb - 2;
  float m0=0.f,m1=0.f,m2=0.f,m3=0.f;
  if (wo >= 0 && wo < WPAD){
    m0=m1=m2=m3=-1e30f;
    #pragma unroll
    for (int kh = 0; kh < 3; ++kh){
      const u16* row = in + ((size_t)(n*HH + ho*3 + kh)*WST + 2)*OC1 + oc;
      #pragma unroll
      for (int kw = 0; kw < 3; ++kw){
        int wi = wo - 1 + kw;
        if (wi >= 0 && wi < WPAD){
          ushort4 v = *(const ushort4*)(row + (size_t)wi*OC1);
          m0 = fmaxf(m0, bf2f(v.x)); m1 = fmaxf(m1, bf2f(v.y));
          m2 = fmaxf(m2, bf2f(v.z)); m3 = fmaxf(m3, bf2f(v.w));
        }
      }
    }
    m0 = (m0>0.f)?m0:0.2f*m0; m1 = (m1>0.f)?m1:0.2f*m1;
    m2 = (m2>0.f)?m2:0.2f*m2; m3 = (m3>0.f)?m3:0.2f*m3;
  }
  ushort4 o; o.x=f2bf(m0); o.y=f2bf(m1); o.z=f2bf(m2); o.w=f2bf(m3);
  *(ushort4*)(out + ((size_t)(n*16 + ho)*WST + wb)*OC1 + oc) = o;
}

// leaky(0.2) + maxpool 4x5 stride(4,1); 4 oc/thread
__global__ __launch_bounds__(256) void pool2k(const u16* __restrict__ in, u16* __restrict__ out){
  int t = threadIdx.x;
  int wb = blockIdx.x*2 + (t >> 7);
  int oc = (t & 127)*4;
  int ho = blockIdx.y, n = blockIdx.z;
  int wo = wb - 2;
  float m0=0.f,m1=0.f,m2=0.f,m3=0.f;
  if (wo >= 0 && wo < WPAD){
    m0=m1=m2=m3=-1e30f;
    #pragma unroll
    for (int kh = 0; kh < 4; ++kh){
      const u16* row = in + ((size_t)(n*16 + ho*4 + kh)*WST + 2)*OC2 + oc;
      #pragma unroll
      for (int kw = 0; kw < 5; ++kw){
        int wi = wo - 2 + kw;
        if (wi >= 0 && wi < WPAD){
          ushort4 v = *(const ushort4*)(row + (size_t)wi*OC2);
          m0 = fmaxf(m0, bf2f(v.x)); m1 = fmaxf(m1, bf2f(v.y));
          m2 = fmaxf(m2, bf2f(v.z)); m3 = fmaxf(m3, bf2f(v.w));
        }
      }
    }
    m0 = (m0>0.f)?m0:0.2f*m0; m1 = (m1>0.f)?m1:0.2f*m1;
    m2 = (m2>0.f)?m2:0.2f*m2; m3 = (m3>0.f)?m3:0.2f*m3;
  }
  ushort4 o; o.x=f2bf(m0); o.y=f2bf(m1); o.z=f2bf(m2); o.w=f2bf(m3);
  *(ushort4*)(out + ((size_t)(n*4 + ho)*WST + wb)*OC2 + oc) = o;
}

// hierarchical pool3 stage A: per-10w-segment max over 4 h rows -> segmax [n][110][1024] fp32
__global__ __launch_bounds__(256) void pool3a(const u16* __restrict__ in, float* __restrict__ segmax){
  int seg = blockIdx.x, n = blockIdx.y;
  int oc = threadIdx.x*4;
  float m0=-1e30f,m1=-1e30f,m2=-1e30f,m3=-1e30f;
  #pragma unroll
  for (int hh = 0; hh < 4; ++hh){
    const u16* row = in + ((size_t)(n*4 + hh)*WST + 2 + seg*10)*OC3 + oc;
    #pragma unroll
    for (int p = 0; p < 10; ++p){
      ushort4 v = *(const ushort4*)(row + (size_t)p*OC3);
      m0 = fmaxf(m0, bf2f(v.x)); m1 = fmaxf(m1, bf2f(v.y));
      m2 = fmaxf(m2, bf2f(v.z)); m3 = fmaxf(m3, bf2f(v.w));
    }
  }
  float* dst = segmax + ((size_t)n*110 + seg)*1024 + oc;
  dst[0]=m0; dst[1]=m1; dst[2]=m2; dst[3]=m3;
}

// combine 20 segment maxes per window, L2 normalize -> xf [row][1024]
__global__ __launch_bounds__(256) void xf_norm(const float* __restrict__ segmax, float* __restrict__ xf){
  int row = blockIdx.x, t = threadIdx.x;
  int n = row / NT, tt = row % NT;
  const float* base = segmax + (size_t)n*110*1024;
  float v[4]; float ss = 0.f;
  #pragma unroll
  for (int j = 0; j < 4; ++j){
    int oc = t + j*256;
    float m = -1e30f;
    #pragma unroll
    for (int u = 0; u < 20; ++u) m = fmaxf(m, base[(size_t)(3*tt + u)*1024 + oc]);
    v[j] = m; ss += m*m;
  }
  #pragma unroll
  for (int m = 1; m < 64; m <<= 1) ss += __shfl_xor(ss, m);
  __shared__ float red[4];
  if ((t & 63) == 0) red[t >> 6] = ss;
  __syncthreads();
  float tot = red[0]+red[1]+red[2]+red[3];
  float inv = 1.f/fmaxf(sqrtf(tot), 1e-12f);
  float* dst = xf + (size_t)row*OC3;
  #pragma unroll
  for (int j = 0; j < 4; ++j) dst[t + j*256] = v[j]*inv;
}

// ---- final head: split-K GEMM ----
__global__ __launch_bounds__(256) void mlp_part(const float* __restrict__ vlad, const float* __restrict__ xf,
    const float* __restrict__ W, float* __restrict__ part){
  __shared__ float feat[4][256];
  int kc = blockIdx.x, rb = blockIdx.y, t = threadIdx.x;
  int i0 = kc*256;
  #pragma unroll
  for (int r = 0; r < 4; ++r){
    int row = rb*4 + r;
    int i = i0 + t;
    feat[r][t] = (i < 8192) ? vlad[(size_t)row*8192 + i] : xf[(size_t)row*1024 + (i - 8192)];
  }
  __syncthreads();
  const float* wr = W + (size_t)t*9216 + i0;
  float a0=0.f, a1=0.f, a2=0.f, a3=0.f;
  for (int i = 0; i < 256; i += 4){
    float4 wv = *(const float4*)&wr[i];
    a0 += feat[0][i]*wv.x + feat[0][i+1]*wv.y + feat[0][i+2]*wv.z + feat[0][i+3]*wv.w;
    a1 += feat[1][i]*wv.x + feat[1][i+1]*wv.y + feat[1][i+2]*wv.z + feat[1][i+3]*wv.w;
    a2 += feat[2][i]*wv.x + feat[2][i+1]*wv.y + feat[2][i+2]*wv.z + feat[2][i+3]*wv.w;
    a3 += feat[3][i]*wv.x + feat[3][i+1]*wv.y + feat[3][i+2]*wv.z + feat[3][i+3]*wv.w;
  }
  float* p0 = part + (((size_t)(rb*4 + 0)*36 + kc))*256 + t;
  p0[0]          = a0;
  p0[36*256]     = a1;
  p0[2*36*256]   = a2;
  p0[3*36*256]   = a3;
}

__global__ __launch_bounds__(256) void mlp_reduce(const float* __restrict__ part, const float* __restrict__ b,
    float* __restrict__ out){
  int row = blockIdx.x, t = threadIdx.x;
  const float* pr = part + (size_t)row*36*256 + t;
  float acc = b[t];
  #pragma unroll
  for (int kc = 0; kc < 36; ++kc) acc += pr[kc*256];
  float ss = acc*acc;
  #pragma unroll
  for (int m = 1; m < 64; m <<= 1) ss += __shfl_xor(ss, m);
  __shared__ float red[4];
  if ((t & 63) == 0) red[t >> 6] = ss;
  __syncthreads();
  float tot = red[0]+red[1]+red[2]+red[3];
  float inv = 1.f/fmaxf(sqrtf(tot), 1e-12f);
  out[(size_t)row*256 + t] = acc*inv;
}

// ---------------- launch ----------------
extern "C" void kernel_launch(void* const* d_in, const int* in_sizes, int n_in,
                              void* d_out, int out_size, void* d_ws, size_t ws_size,
                              hipStream_t stream){
  const float* x       = (const float*)d_in[0];
  const float* centers = (const float*)d_in[1];
  const float* conv_w  = (const float*)d_in[2];
  const float* conv_b  = (const float*)d_in[3];
  const float* w1      = (const float*)d_in[4];
  const float* b1      = (const float*)d_in[5];
  const float* w2      = (const float*)d_in[6];
  const float* b2      = (const float*)d_in[7];
  const float* w3      = (const float*)d_in[8];
  const float* b3      = (const float*)d_in[9];
  const float* mlp_w   = (const float*)d_in[10];
  const float* mlp_b   = (const float*)d_in[11];
  float* out = (float*)d_out;
  char* ws = (char*)d_ws;
  const size_t MB = 1ull << 20;
  if (ws_size < 248*MB) return;

  // persistent small buffers
  float* vlad  = (float*)(ws + 0);        // 3.75 MiB
  float* xf    = (float*)(ws + 4*MB);     // 0.47 MiB
  float* xfraw = (float*)(ws + 5*MB);     // 1.76 MiB (segmax [4][110][1024] fp32)
  char*  AR    = ws + 7*MB;               // arena (241 MiB), phase-reused
  // VLAD phase
  float* a  = (float*)(AR + 85*MB);       // 42.2 MiB (dead after vlad_xa3)
  float* ps = (float*)(AR + 128*MB);      // 14.4 MiB (dead after vlad_win2)
  // conv phase
  u16* xpb = (u16*)(AR + 0);              // 54.4 MiB
  u16* wp1 = (u16*)(AR + 55*MB);          // 1.6 MiB
  u16* wp2 = (u16*)(AR + 57*MB);          // 6.25 MiB
  u16* wp3 = (u16*)(AR + 64*MB);          // 25 MiB
  u16* h1  = (u16*)(AR + 89*MB);          // 108.75 MiB (over a/ps)
  u16* p1  = (u16*)(AR + 0);              // 36.25 MiB (over xpb)
  u16* h2  = (u16*)(AR + 89*MB);          // 72.5 MiB (over h1)
  u16* p2  = (u16*)(AR + 163*MB);         // 18.1 MiB
  u16* h3  = (u16*)(AR + 0);              // 36.25 MiB (over p1)
  float* part = (float*)(AR + 200*MB);    // 4.4 MiB

  // ---- VLAD (fp32) ----
  vlad_softmax<<<dim3(4,HH,NB), 256, 0, stream>>>(x, conv_w, conv_b, a);
  vlad_xa3<<<dim3(110,NB), 256, 0, stream>>>(x, a, centers, ps);
  vlad_win2<<<dim3(KC,NT,NB), 128, 0, stream>>>(ps, vlad);
  vlad_gnorm<<<dim3(NB*NT), 256, 0, stream>>>(vlad);

  // ---- conv tower (128oc x 128w blocks; oc split for finer grid quantization) ----
  pack_w2<<<dim3(3200),  256, 0, stream>>>(w1, wp1, OC1, DIM, 1);
  pack_w2<<<dim3(12800), 256, 0, stream>>>(w2, wp2, OC2, OC1, 2);
  pack_w2<<<dim3(51200), 256, 0, stream>>>(w3, wp3, OC3, OC2, 4);
  build_xpb<<<dim3(37,HH,NB), 256, 0, stream>>>(x, xpb);
  conv5x5<128,256,48><<<dim3(9, OC1/128, NB*HH), 256, 0, stream>>>(xpb, wp1, b1, h1);  // 3456
  pool1k<<<dim3(WST/4,16,NB), 256, 0, stream>>>(h1, p1);
  conv5x5<256,512,16><<<dim3(9, OC2/128, NB*16), 256, 0, stream>>>(p1, wp2, b2, h2);   // 2304
  pool2k<<<dim3(WST/2,4,NB), 256, 0, stream>>>(h2, p2);
  conv5x5<512,1024,4><<<dim3(9, OC3/128, NB*4), 256, 0, stream>>>(p2, wp3, b3, h3);    // 1152
  pool3a<<<dim3(110,NB), 256, 0, stream>>>(h3, xfraw);
  xf_norm<<<dim3(NB*NT), 256, 0, stream>>>(xfraw, xf);

  // ---- head (split-K) ----
  mlp_part<<<dim3(36,30), 256, 0, stream>>>(vlad, xf, mlp_w, part);
  mlp_reduce<<<dim3(NB*NT), 256, 0, stream>>>(part, mlp_b, out);
}

// Round 17
// 1554.656 us; speedup vs baseline: 1.1536x; 1.1153x over previous
//
#include <hip/hip_runtime.h>
#include <hip/hip_bf16.h>

// ---------------- constants ----------------
#define NB   4
#define DIM  128
#define KC   64
#define HH   48
#define WW   900
#define WPAD 1100
#define WST  1160   // guarded stride for conv-phase buffers: col = w + 2, zeros outside [0,1100)
#define NT   30
#define OC1  256
#define OC2  512
#define OC3  1024

typedef __attribute__((ext_vector_type(8))) short bf16x8;
typedef __attribute__((ext_vector_type(4))) float f32x4;
typedef unsigned short u16;
typedef unsigned int u32;

__device__ __forceinline__ u16 f2bf(float f){
  __hip_bfloat16 h = __float2bfloat16(f);
  u16 u; __builtin_memcpy(&u, &h, 2); return u;
}
__device__ __forceinline__ float bf2f(u16 u){
  __hip_bfloat16 h; __builtin_memcpy(&h, &u, 2); return __bfloat162float(h);
}

typedef __attribute__((address_space(1))) const u32 g_u32;
typedef __attribute__((address_space(3))) u32 l_u32;
// async global->LDS, 16B per lane; LDS dest = uniform base + lane*16
__device__ __forceinline__ void gll16(const void* g, void* l){
  __builtin_amdgcn_global_load_lds((g_u32*)g, (l_u32*)l, 16, 0, 0);
}

// ---------------- VLAD branch (fp32) ----------------

__global__ __launch_bounds__(256) void vlad_softmax(const float* __restrict__ x,
    const float* __restrict__ conv_w, const float* __restrict__ conv_b, float* __restrict__ a){
  __shared__ float cwT[DIM*KC];
  __shared__ float cbs[KC];
  int t = threadIdx.x;
  for (int i = t; i < DIM*KC; i += 256){ int c = i >> 6, k = i & 63; cwT[i] = conv_w[k*DIM + c]; }
  if (t < KC) cbs[t] = conv_b[t];
  __syncthreads();
  int w = blockIdx.x*256 + t, h = blockIdx.y, n = blockIdx.z;
  bool ok = (w < WW);
  float lg[KC];
  #pragma unroll
  for (int k = 0; k < KC; ++k) lg[k] = cbs[k];
  const float* xp = x + (size_t)n*DIM*HH*WW + (size_t)h*WW + (ok ? w : 0);
  for (int c = 0; c < DIM; ++c){
    float xv = ok ? xp[(size_t)c*HH*WW] : 0.f;
    const float* cw = &cwT[c*KC];
    #pragma unroll
    for (int k = 0; k < KC; ++k) lg[k] += xv * cw[k];
  }
  float m = lg[0];
  #pragma unroll
  for (int k = 1; k < KC; ++k) m = fmaxf(m, lg[k]);
  float s = 0.f;
  #pragma unroll
  for (int k = 0; k < KC; ++k){ lg[k] = __expf(lg[k]-m); s += lg[k]; }
  float inv = 1.f/s;
  if (ok){
    float* dst = a + (((size_t)(n*HH + h))*WW + w)*KC;
    #pragma unroll
    for (int k = 0; k < KC; k += 4){
      float4 v = make_float4(lg[k]*inv, lg[k+1]*inv, lg[k+2]*inv, lg[k+3]*inv);
      *(float4*)&dst[k] = v;
    }
  }
}

// fused transpose+xa: reads x (NCHW) directly; per (n, segment of 10 padded-w).
__global__ __launch_bounds__(256) void vlad_xa3(const float* __restrict__ x, const float* __restrict__ a,
    const float* __restrict__ centers, float* __restrict__ ps){
  __shared__ float xw[2][10][132];
  __shared__ float aw[2][10][64];
  int t = threadIdx.x, s = blockIdx.x, n = blockIdx.y;
  int k = t >> 2, cb4 = t & 3;
  int p0 = s*10;
  int w0 = (p0 < 100) ? p0 + 800 : ((p0 < 1000) ? p0 - 100 : p0 - 1000);
  const float* xn = x + (size_t)n*DIM*HH*WW + w0;
  const float* an = a + (size_t)n*HH*WW*KC + (size_t)w0*KC;

  auto load = [&](int h, int buf){
    if (t < 128){
      const float* xr = xn + ((size_t)t*HH + h)*WW;
      #pragma unroll
      for (int w = 0; w < 10; ++w) xw[buf][w][t] = xr[w];
    } else {
      const float* ar = an + (size_t)h*WW*KC;
      int e0 = (t - 128)*5;
      #pragma unroll
      for (int q = 0; q < 5; ++q){ int e = e0 + q; aw[buf][e >> 6][e & 63] = ar[e]; }
    }
  };

  float acc[32];
  #pragma unroll
  for (int j = 0; j < 32; ++j) acc[j] = 0.f;
  float Sacc = 0.f;

  load(0, 0);
  for (int h = 0; h < HH; ++h){
    int buf = h & 1;
    __syncthreads();
    if (h + 1 < HH) load(h + 1, buf ^ 1);
    #pragma unroll 2
    for (int w = 0; w < 10; ++w){
      float av = aw[buf][w][k];
      Sacc += av;
      const float4* xr4 = (const float4*)&xw[buf][w][cb4*32];
      #pragma unroll
      for (int jj = 0; jj < 8; ++jj){
        float4 xv = xr4[jj];
        acc[jj*4+0] += av*xv.x; acc[jj*4+1] += av*xv.y;
        acc[jj*4+2] += av*xv.z; acc[jj*4+3] += av*xv.w;
      }
    }
    __syncthreads();
  }

  const float* ck = centers + (size_t)k*DIM + cb4*32;
  float* dst = ps + (((size_t)(n*KC + k))*110 + s)*DIM + cb4*32;
  #pragma unroll
  for (int jj = 0; jj < 8; ++jj){
    float4 o;
    o.x = acc[jj*4+0] - ck[jj*4+0]*Sacc;
    o.y = acc[jj*4+1] - ck[jj*4+1]*Sacc;
    o.z = acc[jj*4+2] - ck[jj*4+2]*Sacc;
    o.w = acc[jj*4+3] - ck[jj*4+3]*Sacc;
    *(float4*)&dst[jj*4] = o;
  }
}

// window tt = segments [3tt, 3tt+20); sum + intra (per-cluster) L2 norm
__global__ __launch_bounds__(128) void vlad_win2(const float* __restrict__ ps, float* __restrict__ vlad){
  int c = threadIdx.x, k = blockIdx.x, tt = blockIdx.y, n = blockIdx.z;
  const float* base = ps + ((size_t)(n*KC + k))*110*DIM + c;
  float v = 0.f;
  #pragma unroll
  for (int u = 0; u < 20; ++u) v += base[(3*tt + u)*DIM];
  float ss = v*v;
  #pragma unroll
  for (int m = 1; m < 64; m <<= 1) ss += __shfl_xor(ss, m);
  __shared__ float red[2];
  if ((c & 63) == 0) red[c >> 6] = ss;
  __syncthreads();
  float tot = red[0] + red[1];
  float inv = 1.f / fmaxf(sqrtf(tot), 1e-12f);
  vlad[(((size_t)(n*NT + tt))*KC + k)*DIM + c] = v*inv;
}

__global__ __launch_bounds__(256) void vlad_gnorm(float* __restrict__ vlad){
  int row = blockIdx.x, t = threadIdx.x;
  float4* v = (float4*)(vlad + (size_t)row*(KC*DIM));
  float4 r[8]; float ss = 0.f;
  #pragma unroll
  for (int i = 0; i < 8; ++i){
    r[i] = v[t + i*256];
    ss += r[i].x*r[i].x + r[i].y*r[i].y + r[i].z*r[i].z + r[i].w*r[i].w;
  }
  #pragma unroll
  for (int m = 1; m < 64; m <<= 1) ss += __shfl_xor(ss, m);
  __shared__ float red[4];
  if ((t & 63) == 0) red[t >> 6] = ss;
  __syncthreads();
  float tot = red[0]+red[1]+red[2]+red[3];
  float inv = 1.f / fmaxf(sqrtf(tot), 1e-12f);
  #pragma unroll
  for (int i = 0; i < 8; ++i){
    float4 o = r[i]; o.x*=inv; o.y*=inv; o.z*=inv; o.w*=inv;
    v[t + i*256] = o;
  }
}

// ---------------- conv tower (bf16 MFMA, NHWC, guarded stride WST) ----------------

__global__ __launch_bounds__(256) void build_xpb(const float* __restrict__ x, u16* __restrict__ xpb){
  __shared__ u16 tile[DIM][33];
  int t = threadIdx.x, h = blockIdx.y, n = blockIdx.z;
  int b0 = blockIdx.x*32;
  #pragma unroll
  for (int i = 0; i < 16; ++i){
    int e = t + i*256;
    int c = e >> 5, bl = e & 31;
    int b = b0 + bl, w = b - 2;
    float v = 0.f;
    if (w >= 0 && w < WPAD){
      int wsrc = (w + 800) % 900;
      v = x[((size_t)(n*DIM + c)*HH + h)*WW + wsrc];
    }
    tile[c][bl] = f2bf(v);
  }
  __syncthreads();
  #pragma unroll
  for (int i = 0; i < 16; ++i){
    int e = t + i*256;
    int bl = e >> 7, c = e & 127;
    int b = b0 + bl;
    if (b < WST) xpb[((size_t)(n*HH + h)*WST + b)*DIM + c] = tile[c][bl];
  }
}

// w OIHW fp32 -> wp fragment layout [tap][icb][k0i][lgp][oc][8ic] bf16
__global__ __launch_bounds__(256) void pack_w2(const float* __restrict__ w, u16* __restrict__ wp,
    int OC, int IC, int NICB){
  int idx = blockIdx.x*256 + threadIdx.x;
  int total = OC*IC*25;
  if (idx >= total) return;
  int e = idx & 7;
  int q = idx >> 3;
  int oc = q % OC;  int q2 = q / OC;
  int lgp = q2 & 3; int k0i = (q2 >> 2) & 3;
  int q3 = q2 >> 4;
  int icb = q3 % NICB; int tap = q3 / NICB;
  int ic = icb*128 + k0i*32 + lgp*8 + e;
  wp[idx] = f2bf(w[((size_t)oc*IC + ic)*25 + tap]);
}

// 5x5 conv pad 2, NHWC bf16, guarded input. Block = 256oc x 128w, 4 waves stacked in
// oc (wave tile 64oc x 128w, acc[4][8]). A-operand global->VGPR from pre-packed
// fragment layout with an explicit depth-2 prefetch ring (static indices only).
// LDS holds only sIn (33 KB single buffer). FINAL CONFIG (round-10 variant, best
// measured 337us/dispatch): round 15 (w-split) doubled weight traffic, round 16
// (oc-split) doubled input-staging traffic -- 256oc x 128w is traffic-minimal.
template<int IC, int OC, int H>
__global__ __launch_bounds__(256,2) void conv5x5(const u16* __restrict__ in, const u16* __restrict__ wp,
    const float* __restrict__ bias, u16* __restrict__ out){
  constexpr int NICB = IC/128;
  __shared__ u16 sIn[132*128];   // rows 0..131 = input w0-2 .. w0+129, 256B/row, chunk-swizzled
  int t = threadIdx.x;
  int wave = t >> 6, lane = t & 63, lr = lane & 15, lgp = lane >> 4;
  int w0  = blockIdx.x * 128;
  int ocb = blockIdx.y * 256;
  int nh = blockIdx.z; int n = nh / H, h = nh % H;
  int wo_oc = wave*64;
  f32x4 acc[4][8] = {};
  const u16* inN = in + (size_t)n*H*WST*IC;   // col0 = w=-2
  const size_t laneA = (size_t)(ocb + wo_oc + lr)*8;  // per-lane A offset within a panel
  for (int dh = 0; dh < 5; ++dh){
    int hin = h + dh - 2;
    if (hin < 0 || hin >= H) continue;
    const u16* rowbase = inN + (size_t)hin*WST*IC;
    for (int icb = 0; icb < NICB; ++icb){
      __syncthreads();  // prior slab's readers done before overwrite
      for (int i = wave; i < 33; i += 4){
        int qq = i*64 + lane;
        int r = qq >> 4, cp = qq & 15;
        int c = cp ^ (r & 7);
        gll16(rowbase + (size_t)(w0 + r)*IC + icb*128 + c*8, &sIn[i*512]);
      }
      __syncthreads();  // staging complete
      // slab weight base: [5 dw][4 k0i][4 lgp][OC][8]
      const u16* wslab = wp + (size_t)(dh*5*NICB + icb)*16*OC*8 + laneA;
      bf16x8 Abuf[3][4];
      #pragma unroll
      for (int pi = 0; pi < 2; ++pi){   // preload i=0,1
        const u16* ap = wslab + (size_t)((pi >> 2)*NICB*16 + ((pi & 3)*4 + lgp))*OC*8;
        #pragma unroll
        for (int ja = 0; ja < 4; ++ja) Abuf[pi][ja] = *(const bf16x8*)(ap + (size_t)ja*16*8);
      }
      #pragma unroll
      for (int dw = 0; dw < 5; ++dw){
        #pragma unroll
        for (int k0i = 0; k0i < 4; ++k0i){
          constexpr int NI = 20;
          const int i = dw*4 + k0i;
          {  // prefetch i+2 into slot (i+2)%3
            const int pn = (i + 2 < NI) ? (i + 2) : (NI - 1);
            const u16* ap = wslab + (size_t)((pn >> 2)*NICB*16 + ((pn & 3)*4 + lgp))*OC*8;
            #pragma unroll
            for (int ja = 0; ja < 4; ++ja) Abuf[(i + 2) % 3][ja] = *(const bf16x8*)(ap + (size_t)ja*16*8);
          }
          bf16x8 B[8];
          #pragma unroll
          for (int jb = 0; jb < 8; ++jb){
            int br = jb*16 + lr + dw;
            B[jb] = *(const bf16x8*)&sIn[br*128 + (((k0i*4 + lgp) ^ (br & 7)) << 3)];
          }
          __builtin_amdgcn_s_setprio(1);
          #pragma unroll
          for (int ja = 0; ja < 4; ++ja)
            #pragma unroll
            for (int jb = 0; jb < 8; ++jb)
              acc[ja][jb] = __builtin_amdgcn_mfma_f32_16x16x32_bf16(Abuf[i % 3][ja], B[jb], acc[ja][jb], 0, 0, 0);
          __builtin_amdgcn_s_setprio(0);
        }
      }
    }
  }
  u16* outP = out + ((size_t)(n*H + h)*WST + 2)*OC;  // col = w+2
  #pragma unroll
  for (int ja = 0; ja < 4; ++ja){
    int oc = ocb + wo_oc + ja*16 + lgp*4;
    float4 bv = *(const float4*)&bias[oc];
    #pragma unroll
    for (int jb = 0; jb < 8; ++jb){
      int wg = w0 + jb*16 + lr;
      if (wg < WPAD){
        f32x4 av = acc[ja][jb];
        ushort4 o;
        o.x = f2bf(av[0] + bv.x);
        o.y = f2bf(av[1] + bv.y);
        o.z = f2bf(av[2] + bv.z);
        o.w = f2bf(av[3] + bv.w);
        *(ushort4*)(outP + (size_t)wg*OC + oc) = o;
      }
    }
  }
}

// leaky(0.2) + maxpool 3x3 stride(3,1); 4 oc/thread
__global__ __launch_bounds__(256) void pool1k(const u16* __restrict__ in, u16* __restrict__ out){
  int t = threadIdx.x;
  int wb = blockIdx.x*4 + (t >> 6);
  int oc = (t & 63)*4;
  int ho = blockIdx.y, n = blockIdx.z;
  int wo = wb - 2;
  float m0=0.f,m1=0.f,m2=0.f,m3=0.f;
  if (wo >= 0 && wo < WPAD){
    m0=m1=m2=m3=-1e30f;
    #pragma unroll
    for (int kh = 0; kh < 3; ++kh){
      const u16* row = in + ((size_t)(n*HH + ho*3 + kh)*WST + 2)*OC1 + oc;
      #pragma unroll
      for (int kw = 0; kw < 3; ++kw){
        int wi = wo - 1 + kw;
        if (wi >= 0 && wi < WPAD){
          ushort4 v = *(const ushort4*)(row + (size_t)wi*OC1);
          m0 = fmaxf(m0, bf2f(v.x)); m1 = fmaxf(m1, bf2f(v.y));
          m2 = fmaxf(m2, bf2f(v.z)); m3 = fmaxf(m3, bf2f(v.w));
        }
      }
    }
    m0 = (m0>0.f)?m0:0.2f*m0; m1 = (m1>0.f)?m1:0.2f*m1;
    m2 = (m2>0.f)?m2:0.2f*m2; m3 = (m3>0.f)?m3:0.2f*m3;
  }
  ushort4 o; o.x=f2bf(m0); o.y=f2bf(m1); o.z=f2bf(m2); o.w=f2bf(m3);
  *(ushort4*)(out + ((size_t)(n*16 + ho)*WST + wb)*OC1 + oc) = o;
}

// leaky(0.2) + maxpool 4x5 stride(4,1); 4 oc/thread
__global__ __launch_bounds__(256) void pool2k(const u16* __restrict__ in, u16* __restrict__ out){
  int t = threadIdx.x;
  int wb = blockIdx.x*2 + (t >> 7);
  int oc = (t & 127)*4;
  int ho = blockIdx.y, n = blockIdx.z;
  int wo = wb - 2;
  float m0=0.f,m1=0.f,m2=0.f,m3=0.f;
  if (wo >= 0 && wo < WPAD){
    m0=m1=m2=m3=-1e30f;
    #pragma unroll
    for (int kh = 0; kh < 4; ++kh){
      const u16* row = in + ((size_t)(n*16 + ho*4 + kh)*WST + 2)*OC2 + oc;
      #pragma unroll
      for (int kw = 0; kw < 5; ++kw){
        int wi = wo - 2 + kw;
        if (wi >= 0 && wi < WPAD){
          ushort4 v = *(const ushort4*)(row + (size_t)wi*OC2);
          m0 = fmaxf(m0, bf2f(v.x)); m1 = fmaxf(m1, bf2f(v.y));
          m2 = fmaxf(m2, bf2f(v.z)); m3 = fmaxf(m3, bf2f(v.w));
        }
      }
    }
    m0 = (m0>0.f)?m0:0.2f*m0; m1 = (m1>0.f)?m1:0.2f*m1;
    m2 = (m2>0.f)?m2:0.2f*m2; m3 = (m3>0.f)?m3:0.2f*m3;
  }
  ushort4 o; o.x=f2bf(m0); o.y=f2bf(m1); o.z=f2bf(m2); o.w=f2bf(m3);
  *(ushort4*)(out + ((size_t)(n*4 + ho)*WST + wb)*OC2 + oc) = o;
}

// hierarchical pool3 stage A: per-10w-segment max over 4 h rows -> segmax [n][110][1024] fp32
__global__ __launch_bounds__(256) void pool3a(const u16* __restrict__ in, float* __restrict__ segmax){
  int seg = blockIdx.x, n = blockIdx.y;
  int oc = threadIdx.x*4;
  float m0=-1e30f,m1=-1e30f,m2=-1e30f,m3=-1e30f;
  #pragma unroll
  for (int hh = 0; hh < 4; ++hh){
    const u16* row = in + ((size_t)(n*4 + hh)*WST + 2 + seg*10)*OC3 + oc;
    #pragma unroll
    for (int p = 0; p < 10; ++p){
      ushort4 v = *(const ushort4*)(row + (size_t)p*OC3);
      m0 = fmaxf(m0, bf2f(v.x)); m1 = fmaxf(m1, bf2f(v.y));
      m2 = fmaxf(m2, bf2f(v.z)); m3 = fmaxf(m3, bf2f(v.w));
    }
  }
  float* dst = segmax + ((size_t)n*110 + seg)*1024 + oc;
  dst[0]=m0; dst[1]=m1; dst[2]=m2; dst[3]=m3;
}

// combine 20 segment maxes per window, L2 normalize -> xf [row][1024]
__global__ __launch_bounds__(256) void xf_norm(const float* __restrict__ segmax, float* __restrict__ xf){
  int row = blockIdx.x, t = threadIdx.x;
  int n = row / NT, tt = row % NT;
  const float* base = segmax + (size_t)n*110*1024;
  float v[4]; float ss = 0.f;
  #pragma unroll
  for (int j = 0; j < 4; ++j){
    int oc = t + j*256;
    float m = -1e30f;
    #pragma unroll
    for (int u = 0; u < 20; ++u) m = fmaxf(m, base[(size_t)(3*tt + u)*1024 + oc]);
    v[j] = m; ss += m*m;
  }
  #pragma unroll
  for (int m = 1; m < 64; m <<= 1) ss += __shfl_xor(ss, m);
  __shared__ float red[4];
  if ((t & 63) == 0) red[t >> 6] = ss;
  __syncthreads();
  float tot = red[0]+red[1]+red[2]+red[3];
  float inv = 1.f/fmaxf(sqrtf(tot), 1e-12f);
  float* dst = xf + (size_t)row*OC3;
  #pragma unroll
  for (int j = 0; j < 4; ++j) dst[t + j*256] = v[j]*inv;
}

// ---- final head: split-K GEMM ----
__global__ __launch_bounds__(256) void mlp_part(const float* __restrict__ vlad, const float* __restrict__ xf,
    const float* __restrict__ W, float* __restrict__ part){
  __shared__ float feat[4][256];
  int kc = blockIdx.x, rb = blockIdx.y, t = threadIdx.x;
  int i0 = kc*256;
  #pragma unroll
  for (int r = 0; r < 4; ++r){
    int row = rb*4 + r;
    int i = i0 + t;
    feat[r][t] = (i < 8192) ? vlad[(size_t)row*8192 + i] : xf[(size_t)row*1024 + (i - 8192)];
  }
  __syncthreads();
  const float* wr = W + (size_t)t*9216 + i0;
  float a0=0.f, a1=0.f, a2=0.f, a3=0.f;
  for (int i = 0; i < 256; i += 4){
    float4 wv = *(const float4*)&wr[i];
    a0 += feat[0][i]*wv.x + feat[0][i+1]*wv.y + feat[0][i+2]*wv.z + feat[0][i+3]*wv.w;
    a1 += feat[1][i]*wv.x + feat[1][i+1]*wv.y + feat[1][i+2]*wv.z + feat[1][i+3]*wv.w;
    a2 += feat[2][i]*wv.x + feat[2][i+1]*wv.y + feat[2][i+2]*wv.z + feat[2][i+3]*wv.w;
    a3 += feat[3][i]*wv.x + feat[3][i+1]*wv.y + feat[3][i+2]*wv.z + feat[3][i+3]*wv.w;
  }
  float* p0 = part + (((size_t)(rb*4 + 0)*36 + kc))*256 + t;
  p0[0]          = a0;
  p0[36*256]     = a1;
  p0[2*36*256]   = a2;
  p0[3*36*256]   = a3;
}

__global__ __launch_bounds__(256) void mlp_reduce(const float* __restrict__ part, const float* __restrict__ b,
    float* __restrict__ out){
  int row = blockIdx.x, t = threadIdx.x;
  const float* pr = part + (size_t)row*36*256 + t;
  float acc = b[t];
  #pragma unroll
  for (int kc = 0; kc < 36; ++kc) acc += pr[kc*256];
  float ss = acc*acc;
  #pragma unroll
  for (int m = 1; m < 64; m <<= 1) ss += __shfl_xor(ss, m);
  __shared__ float red[4];
  if ((t & 63) == 0) red[t >> 6] = ss;
  __syncthreads();
  float tot = red[0]+red[1]+red[2]+red[3];
  float inv = 1.f/fmaxf(sqrtf(tot), 1e-12f);
  out[(size_t)row*256 + t] = acc*inv;
}

// ---------------- launch ----------------
extern "C" void kernel_launch(void* const* d_in, const int* in_sizes, int n_in,
                              void* d_out, int out_size, void* d_ws, size_t ws_size,
                              hipStream_t stream){
  const float* x       = (const float*)d_in[0];
  const float* centers = (const float*)d_in[1];
  const float* conv_w  = (const float*)d_in[2];
  const float* conv_b  = (const float*)d_in[3];
  const float* w1      = (const float*)d_in[4];
  const float* b1      = (const float*)d_in[5];
  const float* w2      = (const float*)d_in[6];
  const float* b2      = (const float*)d_in[7];
  const float* w3      = (const float*)d_in[8];
  const float* b3      = (const float*)d_in[9];
  const float* mlp_w   = (const float*)d_in[10];
  const float* mlp_b   = (const float*)d_in[11];
  float* out = (float*)d_out;
  char* ws = (char*)d_ws;
  const size_t MB = 1ull << 20;
  if (ws_size < 248*MB) return;

  // persistent small buffers
  float* vlad  = (float*)(ws + 0);        // 3.75 MiB
  float* xf    = (float*)(ws + 4*MB);     // 0.47 MiB
  float* xfraw = (float*)(ws + 5*MB);     // 1.76 MiB (segmax [4][110][1024] fp32)
  char*  AR    = ws + 7*MB;               // arena (241 MiB), phase-reused
  // VLAD phase
  float* a  = (float*)(AR + 85*MB);       // 42.2 MiB (dead after vlad_xa3)
  float* ps = (float*)(AR + 128*MB);      // 14.4 MiB (dead after vlad_win2)
  // conv phase
  u16* xpb = (u16*)(AR + 0);              // 54.4 MiB
  u16* wp1 = (u16*)(AR + 55*MB);          // 1.6 MiB
  u16* wp2 = (u16*)(AR + 57*MB);          // 6.25 MiB
  u16* wp3 = (u16*)(AR + 64*MB);          // 25 MiB
  u16* h1  = (u16*)(AR + 89*MB);          // 108.75 MiB (over a/ps)
  u16* p1  = (u16*)(AR + 0);              // 36.25 MiB (over xpb)
  u16* h2  = (u16*)(AR + 89*MB);          // 72.5 MiB (over h1)
  u16* p2  = (u16*)(AR + 163*MB);         // 18.1 MiB
  u16* h3  = (u16*)(AR + 0);              // 36.25 MiB (over p1)
  float* part = (float*)(AR + 200*MB);    // 4.4 MiB

  // ---- VLAD (fp32) ----
  vlad_softmax<<<dim3(4,HH,NB), 256, 0, stream>>>(x, conv_w, conv_b, a);
  vlad_xa3<<<dim3(110,NB), 256, 0, stream>>>(x, a, centers, ps);
  vlad_win2<<<dim3(KC,NT,NB), 128, 0, stream>>>(ps, vlad);
  vlad_gnorm<<<dim3(NB*NT), 256, 0, stream>>>(vlad);

  // ---- conv tower (256oc x 128w, traffic-minimal tiles; round-10 conv) ----
  pack_w2<<<dim3(3200),  256, 0, stream>>>(w1, wp1, OC1, DIM, 1);
  pack_w2<<<dim3(12800), 256, 0, stream>>>(w2, wp2, OC2, OC1, 2);
  pack_w2<<<dim3(51200), 256, 0, stream>>>(w3, wp3, OC3, OC2, 4);
  build_xpb<<<dim3(37,HH,NB), 256, 0, stream>>>(x, xpb);
  conv5x5<128,256,48><<<dim3(9, OC1/256, NB*HH), 256, 0, stream>>>(xpb, wp1, b1, h1);
  pool1k<<<dim3(WST/4,16,NB), 256, 0, stream>>>(h1, p1);
  conv5x5<256,512,16><<<dim3(9, OC2/256, NB*16), 256, 0, stream>>>(p1, wp2, b2, h2);
  pool2k<<<dim3(WST/2,4,NB), 256, 0, stream>>>(h2, p2);
  conv5x5<512,1024,4><<<dim3(9, OC3/256, NB*4), 256, 0, stream>>>(p2, wp3, b3, h3);
  pool3a<<<dim3(110,NB), 256, 0, stream>>>(h3, xfraw);
  xf_norm<<<dim3(NB*NT), 256, 0, stream>>>(xfraw, xf);

  // ---- head (split-K) ----
  mlp_part<<<dim3(36,30), 256, 0, stream>>>(vlad, xf, mlp_w, part);
  mlp_reduce<<<dim3(NB*NT), 256, 0, stream>>>(part, mlp_b, out);
}